// Round 13
// baseline (161.520 us; speedup 1.0000x reference)
//
#include <hip/hip_runtime.h>
#include <hip/hip_bf16.h>
#include <math.h>

#define S_LEN 2048
#define HDIM  2048
#define N_H   16
#define N_KV  2
#define HD_   128
#define NQKV  2560

typedef __attribute__((ext_vector_type(8))) short bf16x8;
typedef __attribute__((ext_vector_type(4))) float f32x4;
typedef __attribute__((ext_vector_type(16))) float f32x16;

#define GLDS16(gsrc, ldst)                                                      \
  __builtin_amdgcn_global_load_lds(                                             \
      (const __attribute__((address_space(1))) void*)(gsrc),                    \
      (__attribute__((address_space(3))) void*)(ldst), 16, 0, 0)

__device__ __forceinline__ ushort f2b(float x) {
  union { __hip_bfloat16 b; ushort u; } c;
  c.b = __float2bfloat16(x);
  return c.u;
}
__device__ __forceinline__ float b2f(ushort u) {
  union { float f; unsigned v; } c;
  c.v = ((unsigned)u) << 16;
  return c.f;
}
__device__ __forceinline__ uint pk2(float a, float b) {
  return (uint)f2b(a) | ((uint)f2b(b) << 16);
}

// ------- prep: x f32->bf16 (blocks 0..4095) + Wq/Wk/Wv transpose ----------
__global__ __launch_bounds__(256) void k_prep(const float* __restrict__ hidden,
                                              const float* __restrict__ Wq,
                                              const float* __restrict__ Wk,
                                              const float* __restrict__ Wv,
                                              ushort* __restrict__ x_b,
                                              ushort* __restrict__ wt) {
  __shared__ float t[64][65];
  const int bid = blockIdx.x;
  const int tid = threadIdx.x;
  if (bid < 4096) {
    const int i = bid * 256 + tid;
    float4 v = ((const float4*)hidden)[i];
    ushort4 o;
    o.x = f2b(v.x); o.y = f2b(v.y); o.z = f2b(v.z); o.w = f2b(v.w);
    ((ushort4*)x_b)[i] = o;
    return;
  }
  int tb = bid - 4096;
  const float* src;
  ushort* dst;
  int C, bx, by;
  if (tb < 1024) {
    src = Wq; dst = wt; C = 2048; bx = tb & 31; by = tb >> 5;
  } else if (tb < 1152) {
    tb -= 1024; src = Wk; dst = wt + (size_t)2048 * 2048; C = 256; bx = tb & 3; by = tb >> 2;
  } else {
    tb -= 1152; src = Wv; dst = wt + (size_t)2304 * 2048; C = 256; bx = tb & 3; by = tb >> 2;
  }
  const int c0 = bx * 64, r0 = by * 64;
  const int tx = tid & 63, ty = tid >> 6;
#pragma unroll
  for (int i = 0; i < 16; ++i)
    t[i * 4 + ty][tx] = src[(size_t)(r0 + i * 4 + ty) * C + (c0 + tx)];
  __syncthreads();
#pragma unroll
  for (int i = 0; i < 16; ++i)
    dst[(size_t)(c0 + i * 4 + ty) * 2048 + (r0 + tx)] = f2b(t[tx][i * 4 + ty]);
}

// ---------------- f32 [R][C] -> bf16 [C][R] tiled transpose (Wo) -----------
__global__ __launch_bounds__(256) void k_transpose_bf16(const float* __restrict__ src,
                                                        ushort* __restrict__ dst,
                                                        int R, int C) {
  __shared__ float t[64][65];
  int c0 = blockIdx.x * 64, r0 = blockIdx.y * 64;
  int tx = threadIdx.x & 63, ty = threadIdx.x >> 6;
#pragma unroll
  for (int i = 0; i < 16; ++i)
    t[i * 4 + ty][tx] = src[(size_t)(r0 + i * 4 + ty) * C + (c0 + tx)];
  __syncthreads();
#pragma unroll
  for (int i = 0; i < 16; ++i)
    dst[(size_t)(c0 + i * 4 + ty) * R + (r0 + tx)] = f2b(t[tx][i * 4 + ty]);
}

// ---- bf16 GEMM 128x128 tile, BK=64, XOR-swizzled LDS (round-10 version) ---
// OUT_MODE 0: bf16 partial slice per z.  OUT_MODE 1: atomicAdd f32 of the
// bf16-rounded half into out (out pre-zeroed; 2 commutative adds/elem ->
// deterministic).
template <int OUT_MODE>
__global__ __launch_bounds__(256) void k_gemm_bt(const ushort* __restrict__ A,
                                                 const ushort* __restrict__ Bt,
                                                 void* __restrict__ Cp,
                                                 int M, int N, int Kfull, int Khalf) {
  __shared__ ushort lA[128 * 64];
  __shared__ ushort lB[128 * 64];
  const int tid = threadIdx.x;
  const int w = tid >> 6, lane = tid & 63;
  const int lr = lane & 15, lg = lane >> 4;
  const int bm = blockIdx.x * 128, bn = blockIdx.y * 128;
  const int wm = (w >> 1) * 64, wn = (w & 1) * 64;
  const int kbeg = blockIdx.z * Khalf;
  f32x4 acc[4][4] = {};

  for (int k0 = kbeg; k0 < kbeg + Khalf; k0 += 64) {
    __syncthreads();
#pragma unroll
    for (int it = 0; it < 4; ++it) {
      const int idx = it * 256 + tid;
      const int row = idx >> 3;
      const int gsl = (idx & 7) ^ (row & 7);  // inverse-swizzled global slot
      GLDS16(A + (size_t)(bm + row) * Kfull + k0 + gsl * 8,
             lA + (it * 256 + w * 64) * 8);
      GLDS16(Bt + (size_t)(bn + row) * Kfull + k0 + gsl * 8,
             lB + (it * 256 + w * 64) * 8);
    }
    __syncthreads();
#pragma unroll
    for (int ks = 0; ks < 2; ++ks) {
      bf16x8 af[4], bf[4];
#pragma unroll
      for (int i = 0; i < 4; ++i) {
        const int ra = wm + i * 16 + lr;
        af[i] = *(const bf16x8*)(lA + ra * 64 + (((ks * 4 + lg) ^ (ra & 7)) * 8));
        const int rb = wn + i * 16 + lr;
        bf[i] = *(const bf16x8*)(lB + rb * 64 + (((ks * 4 + lg) ^ (rb & 7)) * 8));
      }
      __builtin_amdgcn_s_setprio(1);
#pragma unroll
      for (int mi = 0; mi < 4; ++mi)
#pragma unroll
        for (int ni = 0; ni < 4; ++ni)
          acc[mi][ni] =
              __builtin_amdgcn_mfma_f32_16x16x32_bf16(af[mi], bf[ni], acc[mi][ni], 0, 0, 0);
      __builtin_amdgcn_s_setprio(0);
    }
  }

  if (OUT_MODE == 0) {
    ushort* Cout = (ushort*)Cp + (size_t)blockIdx.z * M * N;
#pragma unroll
    for (int mi = 0; mi < 4; ++mi)
#pragma unroll
      for (int ni = 0; ni < 4; ++ni)
#pragma unroll
        for (int r = 0; r < 4; ++r) {
          const int row = bm + wm + mi * 16 + lg * 4 + r;
          const int col = bn + wn + ni * 16 + lr;
          Cout[(size_t)row * N + col] = f2b(acc[mi][ni][r]);
        }
  } else {
    float* O = (float*)Cp;
#pragma unroll
    for (int mi = 0; mi < 4; ++mi)
#pragma unroll
      for (int ni = 0; ni < 4; ++ni)
#pragma unroll
        for (int r = 0; r < 4; ++r) {
          const int row = bm + wm + mi * 16 + lg * 4 + r;
          const int col = bn + wn + ni * 16 + lr;
          atomicAdd(&O[(size_t)row * N + col], b2f(f2b(acc[mi][ni][r])));
        }
  }
}

// ------- fused QKV epilogue (partials+bias, bf16 semantics) + RoPE ---------
__global__ __launch_bounds__(256) void k_epirope(const ushort* __restrict__ p0,
                                                 const ushort* __restrict__ p1,
                                                 const float* __restrict__ bq,
                                                 const float* __restrict__ bk,
                                                 const float* __restrict__ bv,
                                                 const int* __restrict__ pos_ids,
                                                 ushort* __restrict__ q_r,
                                                 ushort* __restrict__ k_r,
                                                 ushort* __restrict__ v_t,
                                                 float* __restrict__ cache_k,
                                                 float* __restrict__ cache_v) {
  const int s = blockIdx.x;
  const int t = threadIdx.x;
  __shared__ float row[NQKV];
  const uint* a = (const uint*)(p0 + (size_t)s * NQKV);
  const uint* b = (const uint*)(p1 + (size_t)s * NQKV);
#pragma unroll
  for (int j = 0; j < 5; ++j) {
    const int c2 = t + 256 * j;  // 1280 uint pairs
    const uint u0 = a[c2], u1 = b[c2];
    const int c = 2 * c2;
    const float v0 = b2f((ushort)u0) + b2f((ushort)(u1 & 0xffff));
    const float v1 = b2f((ushort)(u0 >> 16)) + b2f((ushort)(u1 >> 16));
    const float bias0 = (c < 2048) ? bq[c] : (c < 2304 ? bk[c - 2048] : bv[c - 2304]);
    const float bias1 = (c + 1 < 2048) ? bq[c + 1]
                                       : (c + 1 < 2304 ? bk[c + 1 - 2048] : bv[c + 1 - 2304]);
    row[c] = b2f(f2b(b2f(f2b(v0)) + b2f(f2b(bias0))));
    row[c + 1] = b2f(f2b(b2f(f2b(v1)) + b2f(f2b(bias1))));
  }
  __syncthreads();

  const int i = t & 63, g = t >> 6;
  const float SCALE = 0.08838834764831845f;  // 1/sqrt(128)
  const float pos = (float)pos_ids[s];
  // freq = 1e6^(-i/64) = 2^(-i * log2(1e6)/64); f32 exp2f (no double pow)
  const float freq = exp2f(-0.31143075889569023f * (float)i);
  float sn, cs;
  sincosf(pos * freq, &sn, &cs);

#pragma unroll
  for (int j = 0; j < 4; ++j) {
    const int h = j * 4 + g;
    const float x1 = row[h * 128 + i];
    const float x2 = row[h * 128 + 64 + i];
    const float o1 = x1 * cs - x2 * sn;
    const float o2 = x1 * sn + x2 * cs;
    const size_t qo = ((size_t)h * S_LEN + s) * 128;
    q_r[qo + i] = f2b(o1 * SCALE);
    q_r[qo + 64 + i] = f2b(o2 * SCALE);
  }
  if (g < 2) {
    const int kv = g;
    const float x1 = row[2048 + kv * 128 + i];
    const float x2 = row[2048 + kv * 128 + 64 + i];
    const float o1 = x1 * cs - x2 * sn;
    const float o2 = x1 * sn + x2 * cs;
    const size_t ko = ((size_t)kv * S_LEN + s) * 128;
    k_r[ko + i] = f2b(o1);
    k_r[ko + 64 + i] = f2b(o2);
    const size_t co = ((size_t)s * 2 + kv) * 128;
    cache_k[co + i] = o1;
    cache_k[co + 64 + i] = o2;
  }
  {
    const int kv = t >> 7, d = t & 127;
    const float vval = row[2304 + kv * 128 + d];
    cache_v[((size_t)s * 2 + kv) * 128 + d] = vval;
    v_t[((size_t)kv * 128 + d) * S_LEN + s] = f2b(vval);
  }
}

// ---------------- flash attention: qt64, KV-split-2, double-buffered -------
// (round-5 kernel, best measured: 58.0us, FETCH ~12MB — restored verbatim)
__global__ __launch_bounds__(256, 2) void k_attn(const ushort* __restrict__ q_r,
                                                 const ushort* __restrict__ k_r,
                                                 const ushort* __restrict__ v_t,
                                                 ushort* __restrict__ attn_b) {
  __shared__ ushort smem[2][2][8192];  // [group][buf][K:0..4095 | V:4096..8191]
  __shared__ float stats[2][32][2];

  const int bi = blockIdx.x;
  const int h = bi & 15;
  const int tq = (bi >> 4) & 15;
  const int Q = (bi >> 8) ? (31 - tq) : tq;  // qt64 index, complementary pairs
  const int kvh = h >> 3;

  const int tid = threadIdx.x, w = tid >> 6, lane = tid & 63;
  const int g = w >> 1, wq = w & 1, tg = tid & 127;
  const int l31 = lane & 31, hb = lane >> 5;
  const int S_steps = Q + 1;                 // 32-key tiles per group
  const int qmaxw = Q * 64 + wq * 32 + 31;

  // Q fragments (B-operand): lane holds Q[q=l31][hd = f*16 + 8*hb + j]
  bf16x8 qf[8];
  {
    const ushort* qp =
        q_r + ((size_t)(h * S_LEN + Q * 64 + wq * 32 + l31)) * 128 + hb * 8;
#pragma unroll
    for (int f = 0; f < 8; ++f) qf[f] = *(const bf16x8*)(qp + f * 16);
  }

  f32x16 acc[4] = {};  // O^T: [d-group] row=d, col=q
  float m = -INFINITY, l = 0.f;

#define STAGE(BUF, T32)                                                           \
  do {                                                                            \
    const int kb_ = (T32) * 32;                                                   \
    _Pragma("unroll") for (int i = 0; i < 4; ++i) {                               \
      const int idx = i * 128 + tg;                                               \
      {                                                                           \
        const int key = idx >> 4, sl = idx & 15;                                  \
        GLDS16(k_r + ((size_t)(kvh * S_LEN + kb_ + key)) * 128 +                  \
                   ((sl ^ (key & 7)) * 8),                                        \
               &smem[g][BUF][i * 1024 + wq * 512]);                               \
      }                                                                           \
      {                                                                           \
        const int d = idx >> 2, p = idx & 3;                                      \
        const int gs = (p - (d >> 1)) & 3;                                        \
        GLDS16(v_t + ((size_t)(kvh * HD_ + d)) * S_LEN + kb_ + gs * 8,            \
               &smem[g][BUF][4096 + i * 1024 + wq * 512]);                        \
      }                                                                           \
    }                                                                             \
  } while (0)

  STAGE(0, g);
  int buf = 0;

  for (int s = 0; s < S_steps; ++s) {
    __syncthreads();  // per-wave vmcnt drained before barrier: tile s ready
    if (s + 1 < S_steps) STAGE(buf ^ 1, 2 * (s + 1) + g);
    const int kb = (2 * s + g) * 32;

    if (kb <= qmaxw) {
      const ushort* lK = &smem[g][buf][0];
      const ushort* lV = &smem[g][buf][4096];

      f32x16 p0 = {};
      __builtin_amdgcn_s_setprio(1);
#pragma unroll
      for (int f = 0; f < 8; ++f) {
        const int key = l31;
        const bf16x8 kf8 =
            *(const bf16x8*)(lK + key * 128 + (((2 * f + hb) ^ (key & 7)) * 8));
        p0 = __builtin_amdgcn_mfma_f32_32x32x16_bf16(kf8, qf[f], p0, 0, 0, 0);
      }
      __builtin_amdgcn_s_setprio(0);

      // causal mask + tree max (16 vals/lane)
      const int q = Q * 64 + wq * 32 + l31;
      float sv[16];
#pragma unroll
      for (int r = 0; r < 16; ++r) {
        const int key = kb + (r & 3) + 8 * (r >> 2) + 4 * hb;
        sv[r] = (key <= q) ? p0[r] : -INFINITY;
      }
      float t8[8];
#pragma unroll
      for (int j = 0; j < 8; ++j) t8[j] = fmaxf(sv[j], sv[j + 8]);
#pragma unroll
      for (int st = 4; st >= 1; st >>= 1)
#pragma unroll
        for (int j = 0; j < 4; ++j)
          if (j < st) t8[j] = fmaxf(t8[j], t8[j + st]);
      const float mxw = fmaxf(t8[0], __shfl_xor(t8[0], 32));

      // defer-max (T13)
      if (__any(mxw > m + 8.f)) {
        const float mn = fmaxf(m, mxw);
        const float sc = __expf(m - mn);
#pragma unroll
        for (int g2 = 0; g2 < 4; ++g2)
#pragma unroll
          for (int r = 0; r < 16; ++r) acc[g2][r] *= sc;
        l *= sc;
        m = mn;
      }
#pragma unroll
      for (int r = 0; r < 16; ++r) sv[r] = __expf(sv[r] - m);
      float ts[8];
#pragma unroll
      for (int j = 0; j < 8; ++j) ts[j] = sv[j] + sv[j + 8];
#pragma unroll
      for (int st = 4; st >= 1; st >>= 1)
#pragma unroll
        for (int j = 0; j < 4; ++j)
          if (j < st) ts[j] += ts[j + st];
      l += ts[0];

      // P -> bf16 fragments (cross-half exchange)
      uint pk8[8];
#pragma unroll
      for (int j = 0; j < 8; ++j) pk8[j] = pk2(sv[2 * j], sv[2 * j + 1]);
      union FragU { uint wd[4]; bf16x8 v; };
      FragU frag[2];
#pragma unroll
      for (int c1 = 0; c1 < 2; ++c1) {
        uint mine0, mine1, rcv0, rcv1;
        {
          const uint pa_ = pk8[0 + 4 * c1];
          const uint pb_ = pk8[2 + 4 * c1];
          const uint mn_ = hb ? pb_ : pa_;
          const uint xc_ = hb ? pa_ : pb_;
          mine0 = mn_;
          rcv0 = (uint)__shfl_xor((int)xc_, 32);
        }
        {
          const uint pa_ = pk8[1 + 4 * c1];
          const uint pb_ = pk8[3 + 4 * c1];
          const uint mn_ = hb ? pb_ : pa_;
          const uint xc_ = hb ? pa_ : pb_;
          mine1 = mn_;
          rcv1 = (uint)__shfl_xor((int)xc_, 32);
        }
        frag[c1].wd[0] = hb ? rcv0 : mine0;
        frag[c1].wd[1] = hb ? rcv1 : mine1;
        frag[c1].wd[2] = hb ? mine0 : rcv0;
        frag[c1].wd[3] = hb ? mine1 : rcv1;
      }

      // PV: acc[g2] += V^T[d-group g2] x P
      __builtin_amdgcn_s_setprio(1);
#pragma unroll
      for (int g2 = 0; g2 < 4; ++g2) {
        const int d = g2 * 32 + l31;
#pragma unroll
        for (int c = 0; c < 2; ++c) {
          const int phys = ((2 * c + hb) + (d >> 1)) & 3;
          const bf16x8 vf = *(const bf16x8*)(lV + d * 32 + phys * 8);
          acc[g2] = __builtin_amdgcn_mfma_f32_32x32x16_bf16(vf, frag[c].v, acc[g2], 0, 0, 0);
        }
      }
      __builtin_amdgcn_s_setprio(0);
    }
    buf ^= 1;
  }
  __syncthreads();  // all compute done before smem reuse for merge

  // -------- merge group1 state into group0, then store --------
  float* mrg = (float*)&smem[0][0][0];   // [wq][128 d][32 q] = 32KB
  float* ldsO = (float*)&smem[1][0][0];  // [wq][32 q][128 d] = 32KB
  if (g == 1) {
    const float lt1 = l + __shfl_xor(l, 32);
#pragma unroll
    for (int g2 = 0; g2 < 4; ++g2)
#pragma unroll
      for (int r = 0; r < 16; ++r) {
        const int d5 = (r & 3) + 8 * (r >> 2) + 4 * hb;
        mrg[wq * 4096 + (g2 * 32 + d5) * 32 + l31] = acc[g2][r];
      }
    if (hb == 0) {
      stats[wq][l31][0] = m;
      stats[wq][l31][1] = lt1;
    }
  }
  __syncthreads();
  if (g == 0) {
    const float m1 = stats[wq][l31][0];
    const float l1 = stats[wq][l31][1];
    const float l0 = l + __shfl_xor(l, 32);
    const float ms = fmaxf(m, m1);
    const float f0 = __expf(m - ms);
    const float f1 = __expf(m1 - ms);
    const float inv = 1.0f / (l0 * f0 + l1 * f1);
#pragma unroll
    for (int g2 = 0; g2 < 4; ++g2)
#pragma unroll
      for (int r = 0; r < 16; ++r) {
        const int d5 = (r & 3) + 8 * (r >> 2) + 4 * hb;
        const float o1v = mrg[wq * 4096 + (g2 * 32 + d5) * 32 + l31];
        const float val = (acc[g2][r] * f0 + o1v * f1) * inv;
        ldsO[wq * 4096 + l31 * 128 + g2 * 32 + (d5 ^ l31)] = val;
      }
#pragma unroll
    for (int pass = 0; pass < 8; ++pass) {
      const int qrow = pass * 4 + (lane >> 4);
      const int d0 = (lane & 15) * 8;
      float v[8];
#pragma unroll
      for (int j = 0; j < 8; ++j)
        v[j] = ldsO[wq * 4096 + qrow * 128 + (((d0 + j) & 31) ^ qrow) + (d0 & 96)];
      uint4 o;
      o.x = pk2(v[0], v[1]); o.y = pk2(v[2], v[3]);
      o.z = pk2(v[4], v[5]); o.w = pk2(v[6], v[7]);
      const size_t qg = (size_t)(Q * 64 + wq * 32 + qrow);
      *(uint4*)(attn_b + qg * HDIM + h * 128 + d0) = o;
    }
  }
#undef STAGE
}

// ---------------- launch ----------------
extern "C" void kernel_launch(void* const* d_in, const int* in_sizes, int n_in,
                              void* d_out, int out_size, void* d_ws, size_t ws_size,
                              hipStream_t stream) {
  const float* hidden = (const float*)d_in[0];
  const int* pos_ids = (const int*)d_in[2];
  const float* Wq = (const float*)d_in[3];
  const float* bq = (const float*)d_in[4];
  const float* Wk = (const float*)d_in[5];
  const float* bk = (const float*)d_in[6];
  const float* Wv = (const float*)d_in[7];
  const float* bv = (const float*)d_in[8];
  const float* Wo = (const float*)d_in[9];

  float* out = (float*)d_out;
  float* cache_k = out + (size_t)S_LEN * HDIM;
  float* cache_v = cache_k + (size_t)S_LEN * N_KV * HD_;

  char* ws = (char*)d_ws;
  // MiB layout (peak 38 MiB):
  // P1 (gemm1): x_b 0..8 | wt 8..18 | qkvp p0 18..28, p1 28..38
  // P2: wo_t 10..18 (over wt tail, after gemm1) | q_r 0..8 | k_r 8..9 | v_t 9..10
  // P3 (attn): attn_b 18..26 (over p0)
  // P4 (out gemm): atomicAdd into out (pre-zeroed) — no partials
  ushort* x_b = (ushort*)(ws);
  ushort* wt = (ushort*)(ws + (8ull << 20));
  ushort* qkvp = (ushort*)(ws + (18ull << 20));
  ushort* q_r = (ushort*)(ws);
  ushort* k_r = (ushort*)(ws + (8ull << 20));
  ushort* v_t = (ushort*)(ws + (9ull << 20));
  ushort* wo_t = (ushort*)(ws + (10ull << 20));
  ushort* attn_b = (ushort*)(ws + (18ull << 20));

  hipMemsetAsync(out, 0, (size_t)S_LEN * HDIM * sizeof(float), stream);
  k_prep<<<dim3(5376), 256, 0, stream>>>(hidden, Wq, Wk, Wv, x_b, wt);
  k_gemm_bt<0><<<dim3(16, 20, 2), 256, 0, stream>>>(x_b, wt, qkvp, 2048, 2560, 2048, 1024);
  k_transpose_bf16<<<dim3(32, 32), 256, 0, stream>>>(Wo, wo_t, 2048, 2048);  // wt dead
  k_epirope<<<dim3(S_LEN), 256, 0, stream>>>(qkvp, qkvp + (size_t)2048 * 2560, bq, bk, bv,
                                             pos_ids, q_r, k_r, v_t, cache_k, cache_v);
  k_attn<<<dim3(512), 256, 0, stream>>>(q_r, k_r, v_t, attn_b);
  k_gemm_bt<1><<<dim3(16, 16, 2), 256, 0, stream>>>(attn_b, wo_t, out, 2048, 2048, 2048, 1024);
}

// Round 14
// 139.222 us; speedup vs baseline: 1.1602x; 1.1602x over previous
//
#include <hip/hip_runtime.h>
#include <hip/hip_bf16.h>
#include <math.h>

#define S_LEN 2048
#define HDIM  2048
#define N_H   16
#define N_KV  2
#define HD_   128
#define NQKV  2560

typedef __attribute__((ext_vector_type(8))) short bf16x8;
typedef __attribute__((ext_vector_type(4))) float f32x4;
typedef __attribute__((ext_vector_type(16))) float f32x16;

#define GLDS16(gsrc, ldst)                                                      \
  __builtin_amdgcn_global_load_lds(                                             \
      (const __attribute__((address_space(1))) void*)(gsrc),                    \
      (__attribute__((address_space(3))) void*)(ldst), 16, 0, 0)

__device__ __forceinline__ ushort f2b(float x) {
  union { __hip_bfloat16 b; ushort u; } c;
  c.b = __float2bfloat16(x);
  return c.u;
}
__device__ __forceinline__ float b2f(ushort u) {
  union { float f; unsigned v; } c;
  c.v = ((unsigned)u) << 16;
  return c.f;
}
__device__ __forceinline__ uint pk2(float a, float b) {
  return (uint)f2b(a) | ((uint)f2b(b) << 16);
}

// ------- prep: x f32->bf16 (blocks 0..4095) + Wq/Wk/Wv (+Wo if grid=6400) ---
__global__ __launch_bounds__(256) void k_prep(const float* __restrict__ hidden,
                                              const float* __restrict__ Wq,
                                              const float* __restrict__ Wk,
                                              const float* __restrict__ Wv,
                                              const float* __restrict__ Wo,
                                              ushort* __restrict__ x_b,
                                              ushort* __restrict__ wt,
                                              ushort* __restrict__ wo_t) {
  __shared__ float t[64][65];
  const int bid = blockIdx.x;
  const int tid = threadIdx.x;
  if (bid < 4096) {
    const int i = bid * 256 + tid;
    float4 v = ((const float4*)hidden)[i];
    ushort4 o;
    o.x = f2b(v.x); o.y = f2b(v.y); o.z = f2b(v.z); o.w = f2b(v.w);
    ((ushort4*)x_b)[i] = o;
    return;
  }
  int tb = bid - 4096;
  const float* src;
  ushort* dst;
  int C, bx, by;
  if (tb < 1024) {
    src = Wq; dst = wt; C = 2048; bx = tb & 31; by = tb >> 5;
  } else if (tb < 1152) {
    tb -= 1024; src = Wk; dst = wt + (size_t)2048 * 2048; C = 256; bx = tb & 3; by = tb >> 2;
  } else if (tb < 1280) {
    tb -= 1152; src = Wv; dst = wt + (size_t)2304 * 2048; C = 256; bx = tb & 3; by = tb >> 2;
  } else {
    tb -= 1280; src = Wo; dst = wo_t; C = 2048; bx = tb & 31; by = tb >> 5;
  }
  const int c0 = bx * 64, r0 = by * 64;
  const int tx = tid & 63, ty = tid >> 6;
#pragma unroll
  for (int i = 0; i < 16; ++i)
    t[i * 4 + ty][tx] = src[(size_t)(r0 + i * 4 + ty) * C + (c0 + tx)];
  __syncthreads();
#pragma unroll
  for (int i = 0; i < 16; ++i)
    dst[(size_t)(c0 + i * 4 + ty) * 2048 + (r0 + tx)] = f2b(t[tx][i * 4 + ty]);
}

// ---------------- f32 [R][C] -> bf16 [C][R] tiled transpose (fallback Wo) ---
__global__ __launch_bounds__(256) void k_transpose_bf16(const float* __restrict__ src,
                                                        ushort* __restrict__ dst,
                                                        int R, int C) {
  __shared__ float t[64][65];
  int c0 = blockIdx.x * 64, r0 = blockIdx.y * 64;
  int tx = threadIdx.x & 63, ty = threadIdx.x >> 6;
#pragma unroll
  for (int i = 0; i < 16; ++i)
    t[i * 4 + ty][tx] = src[(size_t)(r0 + i * 4 + ty) * C + (c0 + tx)];
  __syncthreads();
#pragma unroll
  for (int i = 0; i < 16; ++i)
    dst[(size_t)(c0 + i * 4 + ty) * R + (r0 + tx)] = f2b(t[tx][i * 4 + ty]);
}

// ---- bf16 GEMM 128x128 tile, BK=64, XOR-swizzled LDS (round-10 version) ---
__global__ __launch_bounds__(256) void k_gemm_bt(const ushort* __restrict__ A,
                                                 const ushort* __restrict__ Bt,
                                                 ushort* __restrict__ Cp,
                                                 int M, int N, int Kfull, int Khalf) {
  __shared__ ushort lA[128 * 64];
  __shared__ ushort lB[128 * 64];
  const int tid = threadIdx.x;
  const int w = tid >> 6, lane = tid & 63;
  const int lr = lane & 15, lg = lane >> 4;
  const int bm = blockIdx.x * 128, bn = blockIdx.y * 128;
  const int wm = (w >> 1) * 64, wn = (w & 1) * 64;
  const int kbeg = blockIdx.z * Khalf;
  ushort* Cout = Cp + (size_t)blockIdx.z * M * N;
  f32x4 acc[4][4] = {};

  for (int k0 = kbeg; k0 < kbeg + Khalf; k0 += 64) {
    __syncthreads();
#pragma unroll
    for (int it = 0; it < 4; ++it) {
      const int idx = it * 256 + tid;
      const int row = idx >> 3;
      const int gsl = (idx & 7) ^ (row & 7);  // inverse-swizzled global slot
      GLDS16(A + (size_t)(bm + row) * Kfull + k0 + gsl * 8,
             lA + (it * 256 + w * 64) * 8);
      GLDS16(Bt + (size_t)(bn + row) * Kfull + k0 + gsl * 8,
             lB + (it * 256 + w * 64) * 8);
    }
    __syncthreads();
#pragma unroll
    for (int ks = 0; ks < 2; ++ks) {
      bf16x8 af[4], bf[4];
#pragma unroll
      for (int i = 0; i < 4; ++i) {
        const int ra = wm + i * 16 + lr;
        af[i] = *(const bf16x8*)(lA + ra * 64 + (((ks * 4 + lg) ^ (ra & 7)) * 8));
        const int rb = wn + i * 16 + lr;
        bf[i] = *(const bf16x8*)(lB + rb * 64 + (((ks * 4 + lg) ^ (rb & 7)) * 8));
      }
      __builtin_amdgcn_s_setprio(1);
#pragma unroll
      for (int mi = 0; mi < 4; ++mi)
#pragma unroll
        for (int ni = 0; ni < 4; ++ni)
          acc[mi][ni] =
              __builtin_amdgcn_mfma_f32_16x16x32_bf16(af[mi], bf[ni], acc[mi][ni], 0, 0, 0);
      __builtin_amdgcn_s_setprio(0);
    }
  }

#pragma unroll
  for (int mi = 0; mi < 4; ++mi)
#pragma unroll
    for (int ni = 0; ni < 4; ++ni)
#pragma unroll
      for (int r = 0; r < 4; ++r) {
        const int row = bm + wm + mi * 16 + lg * 4 + r;
        const int col = bn + wn + ni * 16 + lr;
        Cout[(size_t)row * N + col] = f2b(acc[mi][ni][r]);
      }
}

// ------- fused QKV epilogue (partials+bias, bf16 semantics) + RoPE ---------
__global__ __launch_bounds__(256) void k_epirope(const ushort* __restrict__ p0,
                                                 const ushort* __restrict__ p1,
                                                 const float* __restrict__ bq,
                                                 const float* __restrict__ bk,
                                                 const float* __restrict__ bv,
                                                 const int* __restrict__ pos_ids,
                                                 ushort* __restrict__ q_r,
                                                 ushort* __restrict__ k_r,
                                                 ushort* __restrict__ v_t,
                                                 float* __restrict__ cache_k,
                                                 float* __restrict__ cache_v) {
  const int s = blockIdx.x;
  const int t = threadIdx.x;
  __shared__ float row[NQKV];
  const uint* a = (const uint*)(p0 + (size_t)s * NQKV);
  const uint* b = (const uint*)(p1 + (size_t)s * NQKV);
#pragma unroll
  for (int j = 0; j < 5; ++j) {
    const int c2 = t + 256 * j;  // 1280 uint pairs
    const uint u0 = a[c2], u1 = b[c2];
    const int c = 2 * c2;
    const float v0 = b2f((ushort)u0) + b2f((ushort)(u1 & 0xffff));
    const float v1 = b2f((ushort)(u0 >> 16)) + b2f((ushort)(u1 >> 16));
    const float bias0 = (c < 2048) ? bq[c] : (c < 2304 ? bk[c - 2048] : bv[c - 2304]);
    const float bias1 = (c + 1 < 2048) ? bq[c + 1]
                                       : (c + 1 < 2304 ? bk[c + 1 - 2048] : bv[c + 1 - 2304]);
    row[c] = b2f(f2b(b2f(f2b(v0)) + b2f(f2b(bias0))));
    row[c + 1] = b2f(f2b(b2f(f2b(v1)) + b2f(f2b(bias1))));
  }
  __syncthreads();

  const int i = t & 63, g = t >> 6;
  const float SCALE = 0.08838834764831845f;  // 1/sqrt(128)
  const float pos = (float)pos_ids[s];
  // freq = 1e6^(-i/64) = 2^(-i * log2(1e6)/64)
  const float freq = exp2f(-0.31143075889569023f * (float)i);
  float sn, cs;
  sincosf(pos * freq, &sn, &cs);

#pragma unroll
  for (int j = 0; j < 4; ++j) {
    const int h = j * 4 + g;
    const float x1 = row[h * 128 + i];
    const float x2 = row[h * 128 + 64 + i];
    const float o1 = x1 * cs - x2 * sn;
    const float o2 = x1 * sn + x2 * cs;
    const size_t qo = ((size_t)h * S_LEN + s) * 128;
    q_r[qo + i] = f2b(o1 * SCALE);
    q_r[qo + 64 + i] = f2b(o2 * SCALE);
  }
  if (g < 2) {
    const int kv = g;
    const float x1 = row[2048 + kv * 128 + i];
    const float x2 = row[2048 + kv * 128 + 64 + i];
    const float o1 = x1 * cs - x2 * sn;
    const float o2 = x1 * sn + x2 * cs;
    const size_t ko = ((size_t)kv * S_LEN + s) * 128;
    k_r[ko + i] = f2b(o1);
    k_r[ko + 64 + i] = f2b(o2);
    const size_t co = ((size_t)s * 2 + kv) * 128;
    cache_k[co + i] = o1;
    cache_k[co + 64 + i] = o2;
  }
  {
    const int kv = t >> 7, d = t & 127;
    const float vval = row[2304 + kv * 128 + d];
    cache_v[((size_t)s * 2 + kv) * 128 + d] = vval;
    v_t[((size_t)kv * 128 + d) * S_LEN + s] = f2b(vval);
  }
}

// ------- out-proj epilogue: add 2 bf16 partial slices, round, f32 out ------
__global__ __launch_bounds__(256) void k_addround(const ushort* __restrict__ p0,
                                                  const ushort* __restrict__ p1,
                                                  float* __restrict__ out, int n2) {
  int i = blockIdx.x * 256 + threadIdx.x;
  if (i >= n2) return;
  const uint a = ((const uint*)p0)[i];
  const uint b = ((const uint*)p1)[i];
  float2 o;
  o.x = b2f(f2b(b2f((ushort)(a & 0xffff)) + b2f((ushort)(b & 0xffff))));
  o.y = b2f(f2b(b2f((ushort)(a >> 16)) + b2f((ushort)(b >> 16))));
  ((float2*)out)[i] = o;
}

// ---------------- flash attention: qt64, KV-split-2, double-buffered -------
// (round-5 kernel, best measured: 58.0us, FETCH ~12MB — kept verbatim)
__global__ __launch_bounds__(256, 2) void k_attn(const ushort* __restrict__ q_r,
                                                 const ushort* __restrict__ k_r,
                                                 const ushort* __restrict__ v_t,
                                                 ushort* __restrict__ attn_b) {
  __shared__ ushort smem[2][2][8192];  // [group][buf][K:0..4095 | V:4096..8191]
  __shared__ float stats[2][32][2];

  const int bi = blockIdx.x;
  const int h = bi & 15;
  const int tq = (bi >> 4) & 15;
  const int Q = (bi >> 8) ? (31 - tq) : tq;  // qt64 index, complementary pairs
  const int kvh = h >> 3;

  const int tid = threadIdx.x, w = tid >> 6, lane = tid & 63;
  const int g = w >> 1, wq = w & 1, tg = tid & 127;
  const int l31 = lane & 31, hb = lane >> 5;
  const int S_steps = Q + 1;                 // 32-key tiles per group
  const int qmaxw = Q * 64 + wq * 32 + 31;

  // Q fragments (B-operand): lane holds Q[q=l31][hd = f*16 + 8*hb + j]
  bf16x8 qf[8];
  {
    const ushort* qp =
        q_r + ((size_t)(h * S_LEN + Q * 64 + wq * 32 + l31)) * 128 + hb * 8;
#pragma unroll
    for (int f = 0; f < 8; ++f) qf[f] = *(const bf16x8*)(qp + f * 16);
  }

  f32x16 acc[4] = {};  // O^T: [d-group] row=d, col=q
  float m = -INFINITY, l = 0.f;

#define STAGE(BUF, T32)                                                           \
  do {                                                                            \
    const int kb_ = (T32) * 32;                                                   \
    _Pragma("unroll") for (int i = 0; i < 4; ++i) {                               \
      const int idx = i * 128 + tg;                                               \
      {                                                                           \
        const int key = idx >> 4, sl = idx & 15;                                  \
        GLDS16(k_r + ((size_t)(kvh * S_LEN + kb_ + key)) * 128 +                  \
                   ((sl ^ (key & 7)) * 8),                                        \
               &smem[g][BUF][i * 1024 + wq * 512]);                               \
      }                                                                           \
      {                                                                           \
        const int d = idx >> 2, p = idx & 3;                                      \
        const int gs = (p - (d >> 1)) & 3;                                        \
        GLDS16(v_t + ((size_t)(kvh * HD_ + d)) * S_LEN + kb_ + gs * 8,            \
               &smem[g][BUF][4096 + i * 1024 + wq * 512]);                        \
      }                                                                           \
    }                                                                             \
  } while (0)

  STAGE(0, g);
  int buf = 0;

  for (int s = 0; s < S_steps; ++s) {
    __syncthreads();  // per-wave vmcnt drained before barrier: tile s ready
    if (s + 1 < S_steps) STAGE(buf ^ 1, 2 * (s + 1) + g);
    const int kb = (2 * s + g) * 32;

    if (kb <= qmaxw) {
      const ushort* lK = &smem[g][buf][0];
      const ushort* lV = &smem[g][buf][4096];

      f32x16 p0 = {};
      __builtin_amdgcn_s_setprio(1);
#pragma unroll
      for (int f = 0; f < 8; ++f) {
        const int key = l31;
        const bf16x8 kf8 =
            *(const bf16x8*)(lK + key * 128 + (((2 * f + hb) ^ (key & 7)) * 8));
        p0 = __builtin_amdgcn_mfma_f32_32x32x16_bf16(kf8, qf[f], p0, 0, 0, 0);
      }
      __builtin_amdgcn_s_setprio(0);

      // causal mask + tree max (16 vals/lane)
      const int q = Q * 64 + wq * 32 + l31;
      float sv[16];
#pragma unroll
      for (int r = 0; r < 16; ++r) {
        const int key = kb + (r & 3) + 8 * (r >> 2) + 4 * hb;
        sv[r] = (key <= q) ? p0[r] : -INFINITY;
      }
      float t8[8];
#pragma unroll
      for (int j = 0; j < 8; ++j) t8[j] = fmaxf(sv[j], sv[j + 8]);
#pragma unroll
      for (int st = 4; st >= 1; st >>= 1)
#pragma unroll
        for (int j = 0; j < 4; ++j)
          if (j < st) t8[j] = fmaxf(t8[j], t8[j + st]);
      const float mxw = fmaxf(t8[0], __shfl_xor(t8[0], 32));

      // defer-max (T13)
      if (__any(mxw > m + 8.f)) {
        const float mn = fmaxf(m, mxw);
        const float sc = __expf(m - mn);
#pragma unroll
        for (int g2 = 0; g2 < 4; ++g2)
#pragma unroll
          for (int r = 0; r < 16; ++r) acc[g2][r] *= sc;
        l *= sc;
        m = mn;
      }
#pragma unroll
      for (int r = 0; r < 16; ++r) sv[r] = __expf(sv[r] - m);
      float ts[8];
#pragma unroll
      for (int j = 0; j < 8; ++j) ts[j] = sv[j] + sv[j + 8];
#pragma unroll
      for (int st = 4; st >= 1; st >>= 1)
#pragma unroll
        for (int j = 0; j < 4; ++j)
          if (j < st) ts[j] += ts[j + st];
      l += ts[0];

      // P -> bf16 fragments (cross-half exchange)
      uint pk8[8];
#pragma unroll
      for (int j = 0; j < 8; ++j) pk8[j] = pk2(sv[2 * j], sv[2 * j + 1]);
      union FragU { uint wd[4]; bf16x8 v; };
      FragU frag[2];
#pragma unroll
      for (int c1 = 0; c1 < 2; ++c1) {
        uint mine0, mine1, rcv0, rcv1;
        {
          const uint pa_ = pk8[0 + 4 * c1];
          const uint pb_ = pk8[2 + 4 * c1];
          const uint mn_ = hb ? pb_ : pa_;
          const uint xc_ = hb ? pa_ : pb_;
          mine0 = mn_;
          rcv0 = (uint)__shfl_xor((int)xc_, 32);
        }
        {
          const uint pa_ = pk8[1 + 4 * c1];
          const uint pb_ = pk8[3 + 4 * c1];
          const uint mn_ = hb ? pb_ : pa_;
          const uint xc_ = hb ? pa_ : pb_;
          mine1 = mn_;
          rcv1 = (uint)__shfl_xor((int)xc_, 32);
        }
        frag[c1].wd[0] = hb ? rcv0 : mine0;
        frag[c1].wd[1] = hb ? rcv1 : mine1;
        frag[c1].wd[2] = hb ? mine0 : rcv0;
        frag[c1].wd[3] = hb ? mine1 : rcv1;
      }

      // PV: acc[g2] += V^T[d-group g2] x P
      __builtin_amdgcn_s_setprio(1);
#pragma unroll
      for (int g2 = 0; g2 < 4; ++g2) {
        const int d = g2 * 32 + l31;
#pragma unroll
        for (int c = 0; c < 2; ++c) {
          const int phys = ((2 * c + hb) + (d >> 1)) & 3;
          const bf16x8 vf = *(const bf16x8*)(lV + d * 32 + phys * 8);
          acc[g2] = __builtin_amdgcn_mfma_f32_32x32x16_bf16(vf, frag[c].v, acc[g2], 0, 0, 0);
        }
      }
      __builtin_amdgcn_s_setprio(0);
    }
    buf ^= 1;
  }
  __syncthreads();  // all compute done before smem reuse for merge

  // -------- merge group1 state into group0, then store --------
  float* mrg = (float*)&smem[0][0][0];   // [wq][128 d][32 q] = 32KB
  float* ldsO = (float*)&smem[1][0][0];  // [wq][32 q][128 d] = 32KB
  if (g == 1) {
    const float lt1 = l + __shfl_xor(l, 32);
#pragma unroll
    for (int g2 = 0; g2 < 4; ++g2)
#pragma unroll
      for (int r = 0; r < 16; ++r) {
        const int d5 = (r & 3) + 8 * (r >> 2) + 4 * hb;
        mrg[wq * 4096 + (g2 * 32 + d5) * 32 + l31] = acc[g2][r];
      }
    if (hb == 0) {
      stats[wq][l31][0] = m;
      stats[wq][l31][1] = lt1;
    }
  }
  __syncthreads();
  if (g == 0) {
    const float m1 = stats[wq][l31][0];
    const float l1 = stats[wq][l31][1];
    const float l0 = l + __shfl_xor(l, 32);
    const float ms = fmaxf(m, m1);
    const float f0 = __expf(m - ms);
    const float f1 = __expf(m1 - ms);
    const float inv = 1.0f / (l0 * f0 + l1 * f1);
#pragma unroll
    for (int g2 = 0; g2 < 4; ++g2)
#pragma unroll
      for (int r = 0; r < 16; ++r) {
        const int d5 = (r & 3) + 8 * (r >> 2) + 4 * hb;
        const float o1v = mrg[wq * 4096 + (g2 * 32 + d5) * 32 + l31];
        const float val = (acc[g2][r] * f0 + o1v * f1) * inv;
        ldsO[wq * 4096 + l31 * 128 + g2 * 32 + (d5 ^ l31)] = val;
      }
#pragma unroll
    for (int pass = 0; pass < 8; ++pass) {
      const int qrow = pass * 4 + (lane >> 4);
      const int d0 = (lane & 15) * 8;
      float v[8];
#pragma unroll
      for (int j = 0; j < 8; ++j)
        v[j] = ldsO[wq * 4096 + qrow * 128 + (((d0 + j) & 31) ^ qrow) + (d0 & 96)];
      uint4 o;
      o.x = pk2(v[0], v[1]); o.y = pk2(v[2], v[3]);
      o.z = pk2(v[4], v[5]); o.w = pk2(v[6], v[7]);
      const size_t qg = (size_t)(Q * 64 + wq * 32 + qrow);
      *(uint4*)(attn_b + qg * HDIM + h * 128 + d0) = o;
    }
  }
#undef STAGE
}

// ---------------- launch ----------------
extern "C" void kernel_launch(void* const* d_in, const int* in_sizes, int n_in,
                              void* d_out, int out_size, void* d_ws, size_t ws_size,
                              hipStream_t stream) {
  const float* hidden = (const float*)d_in[0];
  const int* pos_ids = (const int*)d_in[2];
  const float* Wq = (const float*)d_in[3];
  const float* bq = (const float*)d_in[4];
  const float* Wk = (const float*)d_in[5];
  const float* bk = (const float*)d_in[6];
  const float* Wv = (const float*)d_in[7];
  const float* bv = (const float*)d_in[8];
  const float* Wo = (const float*)d_in[9];

  float* out = (float*)d_out;
  float* cache_k = out + (size_t)S_LEN * HDIM;
  float* cache_v = cache_k + (size_t)S_LEN * N_KV * HD_;

  char* ws = (char*)d_ws;
  // MiB layout (round-10 proven, peak 42; +wo_t@42..50 when ws permits):
  // P1 (gemm1): x_b 0..8 | wt 8..18 | qkvp p0 18..28, p1 28..38
  // P2: q_r 0..8 (over x_b) | k_r 8..9 | v_t 9..10
  // P3 (attn): attn_b 18..26 (over p0)
  // P4 (out gemm): outp 26..42 (over p1)
  // wo_t: 42..50 if ws>=50MiB (written by k_prep), else 10..18 (after gemm1)
  ushort* x_b = (ushort*)(ws);
  ushort* wt = (ushort*)(ws + (8ull << 20));
  ushort* qkvp = (ushort*)(ws + (18ull << 20));
  ushort* q_r = (ushort*)(ws);
  ushort* k_r = (ushort*)(ws + (8ull << 20));
  ushort* v_t = (ushort*)(ws + (9ull << 20));
  ushort* attn_b = (ushort*)(ws + (18ull << 20));
  ushort* outp = (ushort*)(ws + (26ull << 20));

  const bool fuse_wo = (ws_size >= (50ull << 20));
  ushort* wo_t = (ushort*)(ws + (fuse_wo ? (42ull << 20) : (10ull << 20)));

  k_prep<<<dim3(fuse_wo ? 6400 : 5376), 256, 0, stream>>>(hidden, Wq, Wk, Wv, Wo,
                                                          x_b, wt, wo_t);
  k_gemm_bt<<<dim3(16, 20, 2), 256, 0, stream>>>(x_b, wt, qkvp, 2048, 2560, 2048, 1024);
  if (!fuse_wo)
    k_transpose_bf16<<<dim3(32, 32), 256, 0, stream>>>(Wo, wo_t, 2048, 2048);  // wt dead
  k_epirope<<<dim3(S_LEN), 256, 0, stream>>>(qkvp, qkvp + (size_t)2048 * 2560, bq, bk, bv,
                                             pos_ids, q_r, k_r, v_t, cache_k, cache_v);
  k_attn<<<dim3(512), 256, 0, stream>>>(q_r, k_r, v_t, attn_b);
  k_gemm_bt<<<dim3(16, 16, 2), 256, 0, stream>>>(attn_b, wo_t, outp, 2048, 2048, 2048, 1024);
  k_addround<<<dim3((2048 * 2048 / 2 + 255) / 256), 256, 0, stream>>>(
      outp, outp + (size_t)2048 * 2048, out, 2048 * 2048 / 2);
}

// Round 16
// 137.301 us; speedup vs baseline: 1.1764x; 1.0140x over previous
//
#include <hip/hip_runtime.h>
#include <hip/hip_bf16.h>
#include <math.h>

#define S_LEN 2048
#define HDIM  2048
#define N_H   16
#define N_KV  2
#define HD_   128
#define NQKV  2560

typedef __attribute__((ext_vector_type(8))) short bf16x8;
typedef __attribute__((ext_vector_type(4))) float f32x4;
typedef __attribute__((ext_vector_type(16))) float f32x16;

#define GLDS16(gsrc, ldst)                                                      \
  __builtin_amdgcn_global_load_lds(                                             \
      (const __attribute__((address_space(1))) void*)(gsrc),                    \
      (__attribute__((address_space(3))) void*)(ldst), 16, 0, 0)

__device__ __forceinline__ ushort f2b(float x) {
  union { __hip_bfloat16 b; ushort u; } c;
  c.b = __float2bfloat16(x);
  return c.u;
}
__device__ __forceinline__ float b2f(ushort u) {
  union { float f; unsigned v; } c;
  c.v = ((unsigned)u) << 16;
  return c.f;
}
__device__ __forceinline__ uint pk2(float a, float b) {
  return (uint)f2b(a) | ((uint)f2b(b) << 16);
}

// ------- prep: x f32->bf16 (blocks 0..4095) + Wq/Wk/Wv/Wo transpose --------
__global__ __launch_bounds__(256) void k_prep(const float* __restrict__ hidden,
                                              const float* __restrict__ Wq,
                                              const float* __restrict__ Wk,
                                              const float* __restrict__ Wv,
                                              const float* __restrict__ Wo,
                                              ushort* __restrict__ x_b,
                                              ushort* __restrict__ wt,
                                              ushort* __restrict__ wo_t) {
  __shared__ float t[64][65];
  const int bid = blockIdx.x;
  const int tid = threadIdx.x;
  if (bid < 4096) {
    const int i = bid * 256 + tid;
    float4 v = ((const float4*)hidden)[i];
    ushort4 o;
    o.x = f2b(v.x); o.y = f2b(v.y); o.z = f2b(v.z); o.w = f2b(v.w);
    ((ushort4*)x_b)[i] = o;
    return;
  }
  int tb = bid - 4096;
  const float* src;
  ushort* dst;
  int C, bx, by;
  if (tb < 1024) {
    src = Wq; dst = wt; C = 2048; bx = tb & 31; by = tb >> 5;
  } else if (tb < 1152) {
    tb -= 1024; src = Wk; dst = wt + (size_t)2048 * 2048; C = 256; bx = tb & 3; by = tb >> 2;
  } else if (tb < 1280) {
    tb -= 1152; src = Wv; dst = wt + (size_t)2304 * 2048; C = 256; bx = tb & 3; by = tb >> 2;
  } else {
    tb -= 1280; src = Wo; dst = wo_t; C = 2048; bx = tb & 31; by = tb >> 5;
  }
  const int c0 = bx * 64, r0 = by * 64;
  const int tx = tid & 63, ty = tid >> 6;
#pragma unroll
  for (int i = 0; i < 16; ++i)
    t[i * 4 + ty][tx] = src[(size_t)(r0 + i * 4 + ty) * C + (c0 + tx)];
  __syncthreads();
#pragma unroll
  for (int i = 0; i < 16; ++i)
    dst[(size_t)(c0 + i * 4 + ty) * 2048 + (r0 + tx)] = f2b(t[tx][i * 4 + ty]);
}

// ---- bf16 GEMM 128x64 tile, BK=128, XOR-swizzled LDS, no K-split ----------
// OUT_MODE 0: bf16 out (exact ref matmul round).  OUT_MODE 1: f32 out,
// bf16-rounded (exact ref out-proj semantics).
template <int OUT_MODE>
__global__ __launch_bounds__(256) void k_gemm_bt(const ushort* __restrict__ A,
                                                 const ushort* __restrict__ Bt,
                                                 void* __restrict__ Cp,
                                                 int M, int N, int K) {
  __shared__ ushort lA[128 * 128];  // 32KB
  __shared__ ushort lB[64 * 128];   // 16KB
  const int tid = threadIdx.x;
  const int w = tid >> 6, lane = tid & 63;
  const int lr = lane & 15, lg = lane >> 4;
  const int bm = blockIdx.x * 128, bn = blockIdx.y * 64;
  const int wm = (w >> 1) * 64, wn = (w & 1) * 32;
  f32x4 acc[4][2] = {};

  for (int k0 = 0; k0 < K; k0 += 128) {
    __syncthreads();
#pragma unroll
    for (int it = 0; it < 8; ++it) {  // A: 128 rows x 16 slots of 16B
      const int idx = it * 256 + tid;
      const int row = idx >> 4;
      const int gsl = (idx & 15) ^ (row & 15);  // inverse-swizzled global slot
      GLDS16(A + (size_t)(bm + row) * K + k0 + gsl * 8,
             lA + (it * 256 + w * 64) * 8);  // x8 ushorts = 16B/slot
    }
#pragma unroll
    for (int it = 0; it < 4; ++it) {  // B: 64 rows x 16 slots
      const int idx = it * 256 + tid;
      const int row = idx >> 4;
      const int gsl = (idx & 15) ^ (row & 15);
      GLDS16(Bt + (size_t)(bn + row) * K + k0 + gsl * 8,
             lB + (it * 256 + w * 64) * 8);
    }
    __syncthreads();
#pragma unroll
    for (int ks = 0; ks < 4; ++ks) {
      bf16x8 af[4], bf[2];
#pragma unroll
      for (int i = 0; i < 4; ++i) {
        const int ra = wm + i * 16 + lr;
        af[i] = *(const bf16x8*)(lA + ra * 128 + (((ks * 4 + lg) ^ (ra & 15)) * 8));
      }
#pragma unroll
      for (int i = 0; i < 2; ++i) {
        const int rb = wn + i * 16 + lr;
        bf[i] = *(const bf16x8*)(lB + rb * 128 + (((ks * 4 + lg) ^ (rb & 15)) * 8));
      }
      __builtin_amdgcn_s_setprio(1);
#pragma unroll
      for (int mi = 0; mi < 4; ++mi)
#pragma unroll
        for (int ni = 0; ni < 2; ++ni)
          acc[mi][ni] =
              __builtin_amdgcn_mfma_f32_16x16x32_bf16(af[mi], bf[ni], acc[mi][ni], 0, 0, 0);
      __builtin_amdgcn_s_setprio(0);
    }
  }

#pragma unroll
  for (int mi = 0; mi < 4; ++mi)
#pragma unroll
    for (int ni = 0; ni < 2; ++ni)
#pragma unroll
      for (int r = 0; r < 4; ++r) {
        const int row = bm + wm + mi * 16 + lg * 4 + r;
        const int col = bn + wn + ni * 16 + lr;
        if (OUT_MODE == 0)
          ((ushort*)Cp)[(size_t)row * N + col] = f2b(acc[mi][ni][r]);
        else
          ((float*)Cp)[(size_t)row * N + col] = b2f(f2b(acc[mi][ni][r]));
      }
}

// ------- fused QKV epilogue (bias, bf16 semantics) + RoPE ------------------
__global__ __launch_bounds__(256) void k_epirope(const ushort* __restrict__ qkv,
                                                 const float* __restrict__ bq,
                                                 const float* __restrict__ bk,
                                                 const float* __restrict__ bv,
                                                 const int* __restrict__ pos_ids,
                                                 ushort* __restrict__ q_r,
                                                 ushort* __restrict__ k_r,
                                                 ushort* __restrict__ v_t,
                                                 float* __restrict__ cache_k,
                                                 float* __restrict__ cache_v) {
  const int s = blockIdx.x;
  const int t = threadIdx.x;
  __shared__ float row[NQKV];
  const uint* a = (const uint*)(qkv + (size_t)s * NQKV);
#pragma unroll
  for (int j = 0; j < 5; ++j) {
    const int c2 = t + 256 * j;  // 1280 uint pairs
    const uint u0 = a[c2];
    const int c = 2 * c2;
    const float bias0 = (c < 2048) ? bq[c] : (c < 2304 ? bk[c - 2048] : bv[c - 2304]);
    const float bias1 = (c + 1 < 2048) ? bq[c + 1]
                                       : (c + 1 < 2304 ? bk[c + 1 - 2048] : bv[c + 1 - 2304]);
    row[c] = b2f(f2b(b2f((ushort)(u0 & 0xffff)) + b2f(f2b(bias0))));
    row[c + 1] = b2f(f2b(b2f((ushort)(u0 >> 16)) + b2f(f2b(bias1))));
  }
  __syncthreads();

  const int i = t & 63, g = t >> 6;
  const float SCALE = 0.08838834764831845f;  // 1/sqrt(128)
  const float pos = (float)pos_ids[s];
  // freq = 1e6^(-i/64) = 2^(-i * log2(1e6)/64)
  const float freq = exp2f(-0.31143075889569023f * (float)i);
  float sn, cs;
  sincosf(pos * freq, &sn, &cs);

#pragma unroll
  for (int j = 0; j < 4; ++j) {
    const int h = j * 4 + g;
    const float x1 = row[h * 128 + i];
    const float x2 = row[h * 128 + 64 + i];
    const float o1 = x1 * cs - x2 * sn;
    const float o2 = x1 * sn + x2 * cs;
    const size_t qo = ((size_t)h * S_LEN + s) * 128;
    q_r[qo + i] = f2b(o1 * SCALE);
    q_r[qo + 64 + i] = f2b(o2 * SCALE);
  }
  if (g < 2) {
    const int kv = g;
    const float x1 = row[2048 + kv * 128 + i];
    const float x2 = row[2048 + kv * 128 + 64 + i];
    const float o1 = x1 * cs - x2 * sn;
    const float o2 = x1 * sn + x2 * cs;
    const size_t ko = ((size_t)kv * S_LEN + s) * 128;
    k_r[ko + i] = f2b(o1);
    k_r[ko + 64 + i] = f2b(o2);
    const size_t co = ((size_t)s * 2 + kv) * 128;
    cache_k[co + i] = o1;
    cache_k[co + 64 + i] = o2;
  }
  {
    const int kv = t >> 7, d = t & 127;
    const float vval = row[2304 + kv * 128 + d];
    cache_v[((size_t)s * 2 + kv) * 128 + d] = vval;
    v_t[((size_t)kv * 128 + d) * S_LEN + s] = f2b(vval);
  }
}

// ---------------- flash attention: qt64, KV-split-2, double-buffered -------
// (round-5 kernel, best measured: 58.0us, FETCH ~12MB — kept verbatim)
__global__ __launch_bounds__(256, 2) void k_attn(const ushort* __restrict__ q_r,
                                                 const ushort* __restrict__ k_r,
                                                 const ushort* __restrict__ v_t,
                                                 ushort* __restrict__ attn_b) {
  __shared__ ushort smem[2][2][8192];  // [group][buf][K:0..4095 | V:4096..8191]
  __shared__ float stats[2][32][2];

  const int bi = blockIdx.x;
  const int h = bi & 15;
  const int tq = (bi >> 4) & 15;
  const int Q = (bi >> 8) ? (31 - tq) : tq;  // qt64 index, complementary pairs
  const int kvh = h >> 3;

  const int tid = threadIdx.x, w = tid >> 6, lane = tid & 63;
  const int g = w >> 1, wq = w & 1, tg = tid & 127;
  const int l31 = lane & 31, hb = lane >> 5;
  const int S_steps = Q + 1;                 // 32-key tiles per group
  const int qmaxw = Q * 64 + wq * 32 + 31;

  // Q fragments (B-operand): lane holds Q[q=l31][hd = f*16 + 8*hb + j]
  bf16x8 qf[8];
  {
    const ushort* qp =
        q_r + ((size_t)(h * S_LEN + Q * 64 + wq * 32 + l31)) * 128 + hb * 8;
#pragma unroll
    for (int f = 0; f < 8; ++f) qf[f] = *(const bf16x8*)(qp + f * 16);
  }

  f32x16 acc[4] = {};  // O^T: [d-group] row=d, col=q
  float m = -INFINITY, l = 0.f;

#define STAGE(BUF, T32)                                                           \
  do {                                                                            \
    const int kb_ = (T32) * 32;                                                   \
    _Pragma("unroll") for (int i = 0; i < 4; ++i) {                               \
      const int idx = i * 128 + tg;                                               \
      {                                                                           \
        const int key = idx >> 4, sl = idx & 15;                                  \
        GLDS16(k_r + ((size_t)(kvh * S_LEN + kb_ + key)) * 128 +                  \
                   ((sl ^ (key & 7)) * 8),                                        \
               &smem[g][BUF][i * 1024 + wq * 512]);                               \
      }                                                                           \
      {                                                                           \
        const int d = idx >> 2, p = idx & 3;                                      \
        const int gs = (p - (d >> 1)) & 3;                                        \
        GLDS16(v_t + ((size_t)(kvh * HD_ + d)) * S_LEN + kb_ + gs * 8,            \
               &smem[g][BUF][4096 + i * 1024 + wq * 512]);                        \
      }                                                                           \
    }                                                                             \
  } while (0)

  STAGE(0, g);
  int buf = 0;

  for (int s = 0; s < S_steps; ++s) {
    __syncthreads();  // per-wave vmcnt drained before barrier: tile s ready
    if (s + 1 < S_steps) STAGE(buf ^ 1, 2 * (s + 1) + g);
    const int kb = (2 * s + g) * 32;

    if (kb <= qmaxw) {
      const ushort* lK = &smem[g][buf][0];
      const ushort* lV = &smem[g][buf][4096];

      f32x16 p0 = {};
      __builtin_amdgcn_s_setprio(1);
#pragma unroll
      for (int f = 0; f < 8; ++f) {
        const int key = l31;
        const bf16x8 kf8 =
            *(const bf16x8*)(lK + key * 128 + (((2 * f + hb) ^ (key & 7)) * 8));
        p0 = __builtin_amdgcn_mfma_f32_32x32x16_bf16(kf8, qf[f], p0, 0, 0, 0);
      }
      __builtin_amdgcn_s_setprio(0);

      // causal mask + tree max (16 vals/lane)
      const int q = Q * 64 + wq * 32 + l31;
      float sv[16];
#pragma unroll
      for (int r = 0; r < 16; ++r) {
        const int key = kb + (r & 3) + 8 * (r >> 2) + 4 * hb;
        sv[r] = (key <= q) ? p0[r] : -INFINITY;
      }
      float t8[8];
#pragma unroll
      for (int j = 0; j < 8; ++j) t8[j] = fmaxf(sv[j], sv[j + 8]);
#pragma unroll
      for (int st = 4; st >= 1; st >>= 1)
#pragma unroll
        for (int j = 0; j < 4; ++j)
          if (j < st) t8[j] = fmaxf(t8[j], t8[j + st]);
      const float mxw = fmaxf(t8[0], __shfl_xor(t8[0], 32));

      // defer-max (T13)
      if (__any(mxw > m + 8.f)) {
        const float mn = fmaxf(m, mxw);
        const float sc = __expf(m - mn);
#pragma unroll
        for (int g2 = 0; g2 < 4; ++g2)
#pragma unroll
          for (int r = 0; r < 16; ++r) acc[g2][r] *= sc;
        l *= sc;
        m = mn;
      }
#pragma unroll
      for (int r = 0; r < 16; ++r) sv[r] = __expf(sv[r] - m);
      float ts[8];
#pragma unroll
      for (int j = 0; j < 8; ++j) ts[j] = sv[j] + sv[j + 8];
#pragma unroll
      for (int st = 4; st >= 1; st >>= 1)
#pragma unroll
        for (int j = 0; j < 4; ++j)
          if (j < st) ts[j] += ts[j + st];
      l += ts[0];

      // P -> bf16 fragments (cross-half exchange)
      uint pk8[8];
#pragma unroll
      for (int j = 0; j < 8; ++j) pk8[j] = pk2(sv[2 * j], sv[2 * j + 1]);
      union FragU { uint wd[4]; bf16x8 v; };
      FragU frag[2];
#pragma unroll
      for (int c1 = 0; c1 < 2; ++c1) {
        uint mine0, mine1, rcv0, rcv1;
        {
          const uint pa_ = pk8[0 + 4 * c1];
          const uint pb_ = pk8[2 + 4 * c1];
          const uint mn_ = hb ? pb_ : pa_;
          const uint xc_ = hb ? pa_ : pb_;
          mine0 = mn_;
          rcv0 = (uint)__shfl_xor((int)xc_, 32);
        }
        {
          const uint pa_ = pk8[1 + 4 * c1];
          const uint pb_ = pk8[3 + 4 * c1];
          const uint mn_ = hb ? pb_ : pa_;
          const uint xc_ = hb ? pa_ : pb_;
          mine1 = mn_;
          rcv1 = (uint)__shfl_xor((int)xc_, 32);
        }
        frag[c1].wd[0] = hb ? rcv0 : mine0;
        frag[c1].wd[1] = hb ? rcv1 : mine1;
        frag[c1].wd[2] = hb ? mine0 : rcv0;
        frag[c1].wd[3] = hb ? mine1 : rcv1;
      }

      // PV: acc[g2] += V^T[d-group g2] x P
      __builtin_amdgcn_s_setprio(1);
#pragma unroll
      for (int g2 = 0; g2 < 4; ++g2) {
        const int d = g2 * 32 + l31;
#pragma unroll
        for (int c = 0; c < 2; ++c) {
          const int phys = ((2 * c + hb) + (d >> 1)) & 3;
          const bf16x8 vf = *(const bf16x8*)(lV + d * 32 + phys * 8);
          acc[g2] = __builtin_amdgcn_mfma_f32_32x32x16_bf16(vf, frag[c].v, acc[g2], 0, 0, 0);
        }
      }
      __builtin_amdgcn_s_setprio(0);
    }
    buf ^= 1;
  }
  __syncthreads();  // all compute done before smem reuse for merge

  // -------- merge group1 state into group0, then store --------
  float* mrg = (float*)&smem[0][0][0];   // [wq][128 d][32 q] = 32KB
  float* ldsO = (float*)&smem[1][0][0];  // [wq][32 q][128 d] = 32KB
  if (g == 1) {
    const float lt1 = l + __shfl_xor(l, 32);
#pragma unroll
    for (int g2 = 0; g2 < 4; ++g2)
#pragma unroll
      for (int r = 0; r < 16; ++r) {
        const int d5 = (r & 3) + 8 * (r >> 2) + 4 * hb;
        mrg[wq * 4096 + (g2 * 32 + d5) * 32 + l31] = acc[g2][r];
      }
    if (hb == 0) {
      stats[wq][l31][0] = m;
      stats[wq][l31][1] = lt1;
    }
  }
  __syncthreads();
  if (g == 0) {
    const float m1 = stats[wq][l31][0];
    const float l1 = stats[wq][l31][1];
    const float l0 = l + __shfl_xor(l, 32);
    const float ms = fmaxf(m, m1);
    const float f0 = __expf(m - ms);
    const float f1 = __expf(m1 - ms);
    const float inv = 1.0f / (l0 * f0 + l1 * f1);
#pragma unroll
    for (int g2 = 0; g2 < 4; ++g2)
#pragma unroll
      for (int r = 0; r < 16; ++r) {
        const int d5 = (r & 3) + 8 * (r >> 2) + 4 * hb;
        const float o1v = mrg[wq * 4096 + (g2 * 32 + d5) * 32 + l31];
        const float val = (acc[g2][r] * f0 + o1v * f1) * inv;
        ldsO[wq * 4096 + l31 * 128 + g2 * 32 + (d5 ^ l31)] = val;
      }
#pragma unroll
    for (int pass = 0; pass < 8; ++pass) {
      const int qrow = pass * 4 + (lane >> 4);
      const int d0 = (lane & 15) * 8;
      float v[8];
#pragma unroll
      for (int j = 0; j < 8; ++j)
        v[j] = ldsO[wq * 4096 + qrow * 128 + (((d0 + j) & 31) ^ qrow) + (d0 & 96)];
      uint4 o;
      o.x = pk2(v[0], v[1]); o.y = pk2(v[2], v[3]);
      o.z = pk2(v[4], v[5]); o.w = pk2(v[6], v[7]);
      const size_t qg = (size_t)(Q * 64 + wq * 32 + qrow);
      *(uint4*)(attn_b + qg * HDIM + h * 128 + d0) = o;
    }
  }
#undef STAGE
}

// ---------------- launch ----------------
extern "C" void kernel_launch(void* const* d_in, const int* in_sizes, int n_in,
                              void* d_out, int out_size, void* d_ws, size_t ws_size,
                              hipStream_t stream) {
  const float* hidden = (const float*)d_in[0];
  const int* pos_ids = (const int*)d_in[2];
  const float* Wq = (const float*)d_in[3];
  const float* bq = (const float*)d_in[4];
  const float* Wk = (const float*)d_in[5];
  const float* bk = (const float*)d_in[6];
  const float* Wv = (const float*)d_in[7];
  const float* bv = (const float*)d_in[8];
  const float* Wo = (const float*)d_in[9];

  float* out = (float*)d_out;
  float* cache_k = out + (size_t)S_LEN * HDIM;
  float* cache_v = cache_k + (size_t)S_LEN * N_KV * HD_;

  char* ws = (char*)d_ws;
  // MiB layout (peak 38, under proven-safe 45.6):
  // x_b 0..8 (dead after gemm1) | wt 8..18 (dead after gemm1)
  // qkv 18..28.5 (dead after epirope) | wo_t 30..38 (prep -> gemm2)
  // q_r 0..8 (over x_b) | k_r 8..9 | v_t 9..10 (over wt)
  // attn_b 18..26 (over qkv) | out: d_out direct (gemm2 OUT_MODE 1)
  ushort* x_b = (ushort*)(ws);
  ushort* wt = (ushort*)(ws + (8ull << 20));
  ushort* qkv = (ushort*)(ws + (18ull << 20));
  ushort* wo_t = (ushort*)(ws + (30ull << 20));
  ushort* q_r = (ushort*)(ws);
  ushort* k_r = (ushort*)(ws + (8ull << 20));
  ushort* v_t = (ushort*)(ws + (9ull << 20));
  ushort* attn_b = (ushort*)(ws + (18ull << 20));

  k_prep<<<dim3(6400), 256, 0, stream>>>(hidden, Wq, Wk, Wv, Wo, x_b, wt, wo_t);
  k_gemm_bt<0><<<dim3(16, 40), 256, 0, stream>>>(x_b, wt, qkv, 2048, 2560, 2048);
  k_epirope<<<dim3(S_LEN), 256, 0, stream>>>(qkv, bq, bk, bv, pos_ids, q_r, k_r, v_t,
                                             cache_k, cache_v);
  k_attn<<<dim3(512), 256, 0, stream>>>(q_r, k_r, v_t, attn_b);
  k_gemm_bt<1><<<dim3(16, 32), 256, 0, stream>>>(attn_b, wo_t, out, 2048, 2048, 2048);
}